// Round 7
// baseline (580.732 us; speedup 1.0000x reference)
//
#include <hip/hip_runtime.h>

// CDimSelfAttention: B=4, K=8, T=2048, C=64 -> 32 heads of (2048,64)
// R23: occupancy push. R22 (scratch fixed) left attn ~46us vs 13.7us MFMA
// floor with only 2 waves/SIMD (512 blocks) -- latency/TLP-bound: per-wave
// serial QK->exp->PV path + ~256 L2 fragment loads (~200cyc) with only one
// other wave to fill stalls. Per-wave state is ~116 VGPR, so 4 waves/SIMD
// fit: kt-split x4 -> 1024 blocks (4 blocks/CU), each block = 4 waves
// sharing one 64-q chunk, each wave one kt-quarter (8 tiles). Merge is a
// 2-round LDS tree (waves 2,3 export -> 0,1 add; then 0<->1 exchange by qs;
// 3 barriers, all outside the main loop). lsum pre-reduced to scalar/lane
// before export. All accumulator subscripts compile-time (rule #20).
// launch_bounds(256,4) caps VGPR at 128. LDS 33.8KB x4 blocks = 135KB/CU.
// Main-loop body, fragment layouts (sigma-folded khT A-frags, vtT B-frags),
// base-2 fixed-SOFF softmax: verbatim from verified R22.
// proj kept from R19 (3-sync restructure, verified).

#define T_DIM 2048
#define NHEAD 32
#define HSTRIDE (T_DIM * 64)          // halves per head
#define QSCALE 0.18033688011112042f   // log2(e)/8  (folds 1/sqrt(C) and ln2->log2)
#define SOFF  8.0f                    // constant softmax offset (base-2)

// half-index of 16B group `grp` (0..7) in row `row` (row stride 64 halves), XOR-swizzled
#define SWZ(row, grp) ((row) * 64 + ((((grp) ^ ((row) & 7)) & 7) * 8))

typedef _Float16 h8 __attribute__((ext_vector_type(8)));
typedef _Float16 h4 __attribute__((ext_vector_type(4)));
typedef __fp16   g2 __attribute__((ext_vector_type(2)));
typedef float    f4 __attribute__((ext_vector_type(4)));
typedef float    fv16 __attribute__((ext_vector_type(16)));

union H4U { h4 v; g2 p[2]; };
union H8U { h8 v; h4 h[2]; g2 p[4]; };

#if defined(__has_builtin)
#if __has_builtin(__builtin_amdgcn_exp2f)
#define EXP2(x) __builtin_amdgcn_exp2f(x)
#endif
#endif
#ifndef EXP2
__device__ inline float exp2_raw(float x) {
    float r;
    asm("v_exp_f32 %0, %1" : "=v"(r) : "v"(x));
    return r;
}
#define EXP2(x) exp2_raw(x)
#endif

__device__ inline h4 cvt4(f4 x) {
    H4U u;
    u.p[0] = __builtin_amdgcn_cvt_pkrtz(x[0], x[1]);
    u.p[1] = __builtin_amdgcn_cvt_pkrtz(x[2], x[3]);
    return u.v;
}

__device__ inline h8 cvt8(f4 a, f4 b) {
    H8U r;
    r.h[0] = cvt4(a);
    r.h[1] = cvt4(b);
    return r.v;
}

__device__ inline fv16 splat16(float x) {
    fv16 r;
    #pragma unroll
    for (int i = 0; i < 16; ++i) r[i] = x;
    return r;
}

// ---------------------------------------------------------------------------
// Projection: 1024 blocks x 256 thr; block = 64 t-rows of one head-tile.
// 3 syncthreads total (R19, verified): [stage W+x] | [frags + 24 MFMA] |
// [write layout tiles into ws] | [6 copy-out stores].
// ---------------------------------------------------------------------------
__global__ __launch_bounds__(256) void qkv_proj_kernel(
    const float* __restrict__ x,
    const float* __restrict__ Wq, const float* __restrict__ bq,
    const float* __restrict__ Wk, const float* __restrict__ bk,
    const float* __restrict__ Wv, const float* __restrict__ bv,
    _Float16* __restrict__ qh, _Float16* __restrict__ khT,
    _Float16* __restrict__ vtT)
{
    __shared__ _Float16 ws[3][64 * 64];
    __shared__ float bsh[3][64];

    const int tid  = threadIdx.x;
    const int row0 = blockIdx.x * 64;
    const int head = blockIdx.x >> 5;
    const int t0   = (blockIdx.x & 31) * 64;

    const int w    = tid >> 6;
    const int lane = tid & 63;
    const int l15  = lane & 15;
    const int qd   = lane >> 4;

    // x loads first (longest latency chain)
    f4 xa[2][2];
    {
        const float* xp = x + (size_t)(row0 + w * 16 + l15) * 64 + qd * 8;
        #pragma unroll
        for (int ch = 0; ch < 2; ++ch) {
            xa[ch][0] = *(const f4*)(xp + ch * 32);
            xa[ch][1] = *(const f4*)(xp + ch * 32 + 4);
        }
    }

    #pragma unroll
    for (int m = 0; m < 3; ++m) {
        const float* Wm = (m == 0) ? Wq : ((m == 1) ? Wk : Wv);
        const float* bm = (m == 0) ? bq : ((m == 1) ? bk : bv);
        #pragma unroll
        for (int pass = 0; pass < 4; ++pass) {
            const int idx = pass * 1024 + tid * 4;
            const int d = idx >> 6, c = idx & 63;
            f4 wv = *(const f4*)(Wm + idx);
            *(h4*)&ws[m][SWZ(d, c >> 3) + (c & 7)] = cvt4(wv);
        }
        if (tid < 64) bsh[m][tid] = bm[tid];
    }

    h8 af[2];
    #pragma unroll
    for (int ch = 0; ch < 2; ++ch)
        af[ch] = cvt8(xa[ch][0], xa[ch][1]);

    __syncthreads();                                        // sync 1

    // All frag reads + 24 MFMA (A-fragment shared across q/k/v)
    f4 acc[3][4];
    #pragma unroll
    for (int m = 0; m < 3; ++m) {
        h8 bf[4][2];
        #pragma unroll
        for (int ns = 0; ns < 4; ++ns)
            #pragma unroll
            for (int ch = 0; ch < 2; ++ch)
                bf[ns][ch] = *(const h8*)&ws[m][SWZ(ns * 16 + l15, ch * 4 + qd)];
        #pragma unroll
        for (int ns = 0; ns < 4; ++ns)
            acc[m][ns] = (f4){0.f, 0.f, 0.f, 0.f};
        #pragma unroll
        for (int ch = 0; ch < 2; ++ch)
            #pragma unroll
            for (int ns = 0; ns < 4; ++ns)
                acc[m][ns] = __builtin_amdgcn_mfma_f32_16x16x32_f16(
                    af[ch], bf[ns][ch], acc[m][ns], 0, 0, 0);
    }

    __syncthreads();                                        // sync 2 (ws reads done)

    // Write all three layout tiles into ws[m]
    #pragma unroll
    for (int m = 0; m < 2; ++m) {
        #pragma unroll
        for (int ns = 0; ns < 4; ++ns) {
            const int d = ns * 16 + l15;
            const float bias = bsh[m][d];
            #pragma unroll
            for (int r = 0; r < 4; ++r) {
                const int t = w * 16 + qd * 4 + r;
                float v = acc[m][ns][r] + bias;
                if (m == 0) v *= QSCALE;
                ws[m][SWZ(t, d >> 3) + (d & 7)] = (_Float16)v;
            }
        }
    }
    #pragma unroll
    for (int ns = 0; ns < 4; ++ns) {
        const int d = ns * 16 + l15;
        const float bias = bsh[2][d];
        const int tl = w * 16 + qd * 4;
        f4 pvf;
        #pragma unroll
        for (int r = 0; r < 4; ++r)
            pvf[r] = acc[2][ns][r] + bias;
        *(h4*)&ws[2][SWZ(d, tl >> 3) + (tl & 7)] = cvt4(pvf);
    }

    __syncthreads();                                        // sync 3

    // Copy-outs: all 6 stores issue back-to-back (no more syncs)
    #pragma unroll
    for (int pass = 0; pass < 2; ++pass) {
        const int t  = pass * 32 + (tid >> 3);
        const int c0 = (tid & 7) * 8;
        *(h8*)&qh[(size_t)(row0 + t) * 64 + c0] =
            *(const h8*)&ws[0][SWZ(t, tid & 7)];
    }
    // khT: f = kb*2048 + cs*512 + l*8 + e <->
    //      K_true[t0 + kb*32 + sigma(l&31)][cs*16 + (l>>5)*8 + e]
    #pragma unroll
    for (int pass = 0; pass < 2; ++pass) {
        const int f   = pass * 2048 + tid * 8;
        const int kb  = f >> 11;
        const int cs  = (f >> 9) & 3;
        const int l   = (f >> 3) & 63;
        const int p   = l & 31;
        const int w16 = p & 15;
        const int sw  = ((w16 & 12) == 4) ? (w16 + 4)
                      : (((w16 & 12) == 8) ? (w16 - 4) : w16);
        const int tact = kb * 32 + (p & 16) + sw;
        const int g8   = cs * 2 + (l >> 5);
        *(h8*)&khT[(size_t)head * HSTRIDE + (t0 >> 6) * 4096 + f] =
            *(const h8*)&ws[1][SWZ(tact, g8)];
    }
    // vtT: f = (b*2+cc)*512 + l*8 + e <-> V[t0 + b*16 + (l>>5)*8 + e][cc*32 + (l&31)]
    #pragma unroll
    for (int pass = 0; pass < 2; ++pass) {
        const int f  = pass * 2048 + tid * 8;
        const int q2 = f >> 9;
        const int b  = q2 >> 1, cc = q2 & 1;
        const int l  = (f >> 3) & 63;
        const int c  = cc * 32 + (l & 31);
        const int tg = b * 2 + (l >> 5);
        *(h8*)&vtT[(size_t)head * HSTRIDE + (t0 >> 6) * 4096 + f] =
            *(const h8*)&ws[2][SWZ(c, tg)];
    }
}

// ---------------------------------------------------------------------------
// Flash attention, barrier-free main loop, kt-split x4.
// 1024 blocks x 256 thr = 4 waves/block, 4 blocks/CU (4 waves/SIMD).
// Block = (head, 64-q chunk); wave w covers kt-quarter w (8 tiles of 64 kt).
// K/V fragments loaded straight from L2 (khT/vtT fragment-linear, 16B/lane).
// Merge (fixed-SOFF softmax => partials add linearly):
//   R1: waves 2,3 export (oacc+lsum) -> waves 0,1 add.
//   R2: wave0 exports qs=1 -> wave1; wave1 exports qs=0 -> wave0.
//   Finalize: wave0 stores qs=0 rows, wave1 stores qs=1 rows.
// 3 barriers total. All oacc/ls subscripts compile-time (rule #20).
// ---------------------------------------------------------------------------
__global__ __launch_bounds__(256, 4) void attn_kernel(
    const _Float16* __restrict__ qh, const _Float16* __restrict__ khT,
    const _Float16* __restrict__ vtT, float* __restrict__ out)
{
    __shared__ float xbuf[2][4224];      // 4096 oacc + 128 lsum per exporter

    const int tid  = threadIdx.x;
    const int w    = tid >> 6;          // 0..3 = kt-quarter
    const int lane = tid & 63;
    const int l31  = lane & 31;
    const int lh   = lane >> 5;

    // XCD-aware mapping: all 32 blocks of a head share bid&7 (same XCD)
    const int bid  = blockIdx.x;
    const int xcd  = bid & 7;
    const int idx  = bid >> 3;               // 0..127
    const int head = xcd * 4 + (idx >> 5);
    const int qchunk = idx & 31;
    const int q0   = qchunk * 64;

    // Q B-frags: col = l&31 = q (within 32-block qs), k = 8*lh + e (+16*cs)
    h8 qf[2][4];
    #pragma unroll
    for (int qs = 0; qs < 2; ++qs) {
        const _Float16* qp = qh + (size_t)(head * T_DIM + q0 + qs * 32 + l31) * 64 + lh * 8;
        #pragma unroll
        for (int cs = 0; cs < 4; ++cs)
            qf[qs][cs] = *(const h8*)(qp + cs * 16);
    }

    const int ko = lane * 8;
    const _Float16* kbase = khT + (size_t)head * HSTRIDE + (size_t)w * 8 * 4096;
    const _Float16* vbase = vtT + (size_t)head * HSTRIDE + (size_t)w * 8 * 4096;

    f4 rs4[2] = {(f4){0.f,0.f,0.f,0.f}, (f4){0.f,0.f,0.f,0.f}};
    fv16 oacc[2][2];
    #pragma unroll
    for (int qs = 0; qs < 2; ++qs)
        #pragma unroll
        for (int cc = 0; cc < 2; ++cc)
            oacc[qs][cc] = splat16(0.f);

    // prologue: fragment loads for tile 0 of this quarter
    h8 kf[2][4];
    h8 vf[4][2];
    #pragma unroll
    for (int kb = 0; kb < 2; ++kb)
        #pragma unroll
        for (int cs = 0; cs < 4; ++cs)
            kf[kb][cs] = *(const h8*)(kbase + kb * 2048 + cs * 512 + ko);
    #pragma unroll
    for (int b = 0; b < 4; ++b)
        #pragma unroll
        for (int cc = 0; cc < 2; ++cc)
            vf[b][cc] = *(const h8*)(vbase + (b * 2 + cc) * 512 + ko);

    for (int it = 0; it < 8; ++it) {
        const _Float16* kn = kbase + (size_t)(it + 1) * 4096;
        const _Float16* vn = vbase + (size_t)(it + 1) * 4096;
        const bool more = (it < 7);

        #pragma unroll
        for (int kb = 0; kb < 2; ++kb) {
            // QK for this kb (st kept to 32 regs: 2 qs x fv16)
            fv16 st2[2];
            st2[0] = splat16(-SOFF);
            st2[1] = splat16(-SOFF);
            #pragma unroll
            for (int cs = 0; cs < 4; ++cs)
                #pragma unroll
                for (int qs = 0; qs < 2; ++qs)
                    st2[qs] = __builtin_amdgcn_mfma_f32_32x32x16_f16(
                        kf[kb][cs], qf[qs][cs], st2[qs], 0, 0, 0);

            // kf[kb] dead after QK issue -> reload next tile's kb block now;
            // the L2 load drains under the exp/PV below.
            if (more) {
                #pragma unroll
                for (int cs = 0; cs < 4; ++cs)
                    kf[kb][cs] = *(const h8*)(kn + kb * 2048 + cs * 512 + ko);
            }

            // softmax + PV for this kb
            #pragma unroll
            for (int qs = 0; qs < 2; ++qs) {
                f4 pg[4];
                #pragma unroll
                for (int g = 0; g < 4; ++g) {
                    pg[g][0] = EXP2(st2[qs][4 * g + 0]);
                    pg[g][1] = EXP2(st2[qs][4 * g + 1]);
                    pg[g][2] = EXP2(st2[qs][4 * g + 2]);
                    pg[g][3] = EXP2(st2[qs][4 * g + 3]);
                    rs4[qs] += pg[g];
                }
                H8U pa[2];
                #pragma unroll
                for (int g = 0; g < 4; ++g) {
                    pa[g >> 1].p[(g & 1) * 2 + 0] = __builtin_amdgcn_cvt_pkrtz(pg[g][0], pg[g][1]);
                    pa[g >> 1].p[(g & 1) * 2 + 1] = __builtin_amdgcn_cvt_pkrtz(pg[g][2], pg[g][3]);
                }
                #pragma unroll
                for (int bl = 0; bl < 2; ++bl)
                    #pragma unroll
                    for (int cc = 0; cc < 2; ++cc)
                        oacc[qs][cc] = __builtin_amdgcn_mfma_f32_32x32x16_f16(
                            pa[bl].v, vf[kb * 2 + bl][cc], oacc[qs][cc], 0, 0, 0);
            }

            // vf blocks for this kb dead -> reload next tile's; drains under
            // the next kb's / next iter's QK+exp.
            if (more) {
                #pragma unroll
                for (int bl = 0; bl < 2; ++bl)
                    #pragma unroll
                    for (int cc = 0; cc < 2; ++cc)
                        vf[kb * 2 + bl][cc] =
                            *(const h8*)(vn + ((kb * 2 + bl) * 2 + cc) * 512 + ko);
            }
        }
    }

    // pre-reduce rs to one scalar per lane per qs (value for q-col l31)
    float ls0, ls1;
    {
        float a = (rs4[0][0] + rs4[0][1]) + (rs4[0][2] + rs4[0][3]);
        a += __shfl_xor(a, 32, 64);
        ls0 = a;
        float b = (rs4[1][0] + rs4[1][1]) + (rs4[1][2] + rs4[1][3]);
        b += __shfl_xor(b, 32, 64);
        ls1 = b;
    }

    // ---- Round 1: waves 2,3 export everything; waves 0,1 add ----
    if (w >= 2) {
        float* xb = xbuf[w - 2];
        #pragma unroll
        for (int qs = 0; qs < 2; ++qs)
            #pragma unroll
            for (int cc = 0; cc < 2; ++cc)
                #pragma unroll
                for (int r = 0; r < 16; ++r)
                    xb[(qs * 2 + cc) * 1024 + r * 64 + lane] = oacc[qs][cc][r];
        xb[4096 + lane] = ls0;
        xb[4160 + lane] = ls1;
    }
    __syncthreads();                                       // barrier 1
    if (w < 2) {
        const float* xb = xbuf[w];
        #pragma unroll
        for (int qs = 0; qs < 2; ++qs)
            #pragma unroll
            for (int cc = 0; cc < 2; ++cc)
                #pragma unroll
                for (int r = 0; r < 16; ++r)
                    oacc[qs][cc][r] += xb[(qs * 2 + cc) * 1024 + r * 64 + lane];
        ls0 += xb[4096 + lane];
        ls1 += xb[4160 + lane];
    }
    __syncthreads();                                       // barrier 2

    // ---- Round 2: wave0 exports qs=1 (to wave1); wave1 exports qs=0 ----
    if (w == 0) {
        float* xb = xbuf[1];
        #pragma unroll
        for (int cc = 0; cc < 2; ++cc)
            #pragma unroll
            for (int r = 0; r < 16; ++r)
                xb[(2 + cc) * 1024 + r * 64 + lane] = oacc[1][cc][r];
        xb[4160 + lane] = ls1;
    } else if (w == 1) {
        float* xb = xbuf[0];
        #pragma unroll
        for (int cc = 0; cc < 2; ++cc)
            #pragma unroll
            for (int r = 0; r < 16; ++r)
                xb[cc * 1024 + r * 64 + lane] = oacc[0][cc][r];
        xb[4096 + lane] = ls0;
    }
    __syncthreads();                                       // barrier 3

    // ---- Finalize: wave0 -> qs=0 rows, wave1 -> qs=1 rows ----
    if (w == 0) {
        const float* xb = xbuf[0];
        fv16 of[2];
        #pragma unroll
        for (int cc = 0; cc < 2; ++cc)
            #pragma unroll
            for (int r = 0; r < 16; ++r)
                of[cc][r] = oacc[0][cc][r] + xb[cc * 1024 + r * 64 + lane];
        const float lt = ls0 + xb[4096 + lane];
        const float linv = 1.f / lt;
        #pragma unroll
        for (int r = 0; r < 16; ++r) {
            const int qrow = (r & 3) + 8 * (r >> 2) + 4 * lh;
            const float fac = __shfl(linv, qrow, 64);
            #pragma unroll
            for (int cc = 0; cc < 2; ++cc)
                out[(size_t)(head * T_DIM + q0 + qrow) * 64 + cc * 32 + l31] =
                    of[cc][r] * fac;
        }
    } else if (w == 1) {
        const float* xb = xbuf[1];
        fv16 of[2];
        #pragma unroll
        for (int cc = 0; cc < 2; ++cc)
            #pragma unroll
            for (int r = 0; r < 16; ++r)
                of[cc][r] = oacc[1][cc][r] + xb[(2 + cc) * 1024 + r * 64 + lane];
        const float lt = ls1 + xb[4160 + lane];
        const float linv = 1.f / lt;
        #pragma unroll
        for (int r = 0; r < 16; ++r) {
            const int qrow = (r & 3) + 8 * (r >> 2) + 4 * lh;
            const float fac = __shfl(linv, qrow, 64);
            #pragma unroll
            for (int cc = 0; cc < 2; ++cc)
                out[(size_t)(head * T_DIM + q0 + 32 + qrow) * 64 + cc * 32 + l31] =
                    of[cc][r] * fac;
        }
    }
}

extern "C" void kernel_launch(void* const* d_in, const int* in_sizes, int n_in,
                              void* d_out, int out_size, void* d_ws, size_t ws_size,
                              hipStream_t stream)
{
    (void)in_sizes; (void)n_in; (void)out_size; (void)ws_size;
    const float* x  = (const float*)d_in[0];
    const float* Wq = (const float*)d_in[1];
    const float* bq = (const float*)d_in[2];
    const float* Wk = (const float*)d_in[3];
    const float* bk = (const float*)d_in[4];
    const float* Wv = (const float*)d_in[5];
    const float* bv = (const float*)d_in[6];
    float* out = (float*)d_out;

    _Float16* qh  = (_Float16*)d_ws;
    _Float16* khT = qh + (size_t)NHEAD * HSTRIDE;
    _Float16* vtT = khT + (size_t)NHEAD * HSTRIDE;

    hipLaunchKernelGGL(qkv_proj_kernel, dim3(1024), dim3(256), 0, stream,
                       x, Wq, bq, Wk, bk, Wv, bv, qh, khT, vtT);
    hipLaunchKernelGGL(attn_kernel, dim3(1024), dim3(256), 0, stream,
                       qh, khT, vtT, out);
}

// Round 8
// 123.377 us; speedup vs baseline: 4.7070x; 4.7070x over previous
//
#include <hip/hip_runtime.h>

// CDimSelfAttention: B=4, K=8, T=2048, C=64 -> 32 heads of (2048,64)
// R24: R23 with the launch-bounds poison removed. R23's counters: VGPR 64
// (forced cap from __launch_bounds__(256,4) = 8-waves/EU budget, not the
// 128 intended), 2.4GB scratch traffic, 555us. The kt-split-x4 structure
// itself passed verification. Fix: __launch_bounds__(256,2) -- R22-verified
// codegen at 116 VGPR, which is ALREADY <=128, the HW threshold for
// 4 waves/SIMD. So the 1024-block grid (4 blocks/CU, LDS 33.8KBx4=135KB)
// reaches 16 waves/CU naturally without any allocator squeeze.
// Everything else verbatim R23: barrier-free main loop, K/V fragments
// straight from L2 (khT/vtT fragment-linear), kt-quarter per wave,
// 2-round LDS merge tree (3 barriers, outside the loop), static subscripts
// everywhere (rule #20).
// proj kept from R19 (3-sync restructure, verified).

#define T_DIM 2048
#define NHEAD 32
#define HSTRIDE (T_DIM * 64)          // halves per head
#define QSCALE 0.18033688011112042f   // log2(e)/8  (folds 1/sqrt(C) and ln2->log2)
#define SOFF  8.0f                    // constant softmax offset (base-2)

// half-index of 16B group `grp` (0..7) in row `row` (row stride 64 halves), XOR-swizzled
#define SWZ(row, grp) ((row) * 64 + ((((grp) ^ ((row) & 7)) & 7) * 8))

typedef _Float16 h8 __attribute__((ext_vector_type(8)));
typedef _Float16 h4 __attribute__((ext_vector_type(4)));
typedef __fp16   g2 __attribute__((ext_vector_type(2)));
typedef float    f4 __attribute__((ext_vector_type(4)));
typedef float    fv16 __attribute__((ext_vector_type(16)));

union H4U { h4 v; g2 p[2]; };
union H8U { h8 v; h4 h[2]; g2 p[4]; };

#if defined(__has_builtin)
#if __has_builtin(__builtin_amdgcn_exp2f)
#define EXP2(x) __builtin_amdgcn_exp2f(x)
#endif
#endif
#ifndef EXP2
__device__ inline float exp2_raw(float x) {
    float r;
    asm("v_exp_f32 %0, %1" : "=v"(r) : "v"(x));
    return r;
}
#define EXP2(x) exp2_raw(x)
#endif

__device__ inline h4 cvt4(f4 x) {
    H4U u;
    u.p[0] = __builtin_amdgcn_cvt_pkrtz(x[0], x[1]);
    u.p[1] = __builtin_amdgcn_cvt_pkrtz(x[2], x[3]);
    return u.v;
}

__device__ inline h8 cvt8(f4 a, f4 b) {
    H8U r;
    r.h[0] = cvt4(a);
    r.h[1] = cvt4(b);
    return r.v;
}

__device__ inline fv16 splat16(float x) {
    fv16 r;
    #pragma unroll
    for (int i = 0; i < 16; ++i) r[i] = x;
    return r;
}

// ---------------------------------------------------------------------------
// Projection: 1024 blocks x 256 thr; block = 64 t-rows of one head-tile.
// 3 syncthreads total (R19, verified): [stage W+x] | [frags + 24 MFMA] |
// [write layout tiles into ws] | [6 copy-out stores].
// ---------------------------------------------------------------------------
__global__ __launch_bounds__(256) void qkv_proj_kernel(
    const float* __restrict__ x,
    const float* __restrict__ Wq, const float* __restrict__ bq,
    const float* __restrict__ Wk, const float* __restrict__ bk,
    const float* __restrict__ Wv, const float* __restrict__ bv,
    _Float16* __restrict__ qh, _Float16* __restrict__ khT,
    _Float16* __restrict__ vtT)
{
    __shared__ _Float16 ws[3][64 * 64];
    __shared__ float bsh[3][64];

    const int tid  = threadIdx.x;
    const int row0 = blockIdx.x * 64;
    const int head = blockIdx.x >> 5;
    const int t0   = (blockIdx.x & 31) * 64;

    const int w    = tid >> 6;
    const int lane = tid & 63;
    const int l15  = lane & 15;
    const int qd   = lane >> 4;

    // x loads first (longest latency chain)
    f4 xa[2][2];
    {
        const float* xp = x + (size_t)(row0 + w * 16 + l15) * 64 + qd * 8;
        #pragma unroll
        for (int ch = 0; ch < 2; ++ch) {
            xa[ch][0] = *(const f4*)(xp + ch * 32);
            xa[ch][1] = *(const f4*)(xp + ch * 32 + 4);
        }
    }

    #pragma unroll
    for (int m = 0; m < 3; ++m) {
        const float* Wm = (m == 0) ? Wq : ((m == 1) ? Wk : Wv);
        const float* bm = (m == 0) ? bq : ((m == 1) ? bk : bv);
        #pragma unroll
        for (int pass = 0; pass < 4; ++pass) {
            const int idx = pass * 1024 + tid * 4;
            const int d = idx >> 6, c = idx & 63;
            f4 wv = *(const f4*)(Wm + idx);
            *(h4*)&ws[m][SWZ(d, c >> 3) + (c & 7)] = cvt4(wv);
        }
        if (tid < 64) bsh[m][tid] = bm[tid];
    }

    h8 af[2];
    #pragma unroll
    for (int ch = 0; ch < 2; ++ch)
        af[ch] = cvt8(xa[ch][0], xa[ch][1]);

    __syncthreads();                                        // sync 1

    // All frag reads + 24 MFMA (A-fragment shared across q/k/v)
    f4 acc[3][4];
    #pragma unroll
    for (int m = 0; m < 3; ++m) {
        h8 bf[4][2];
        #pragma unroll
        for (int ns = 0; ns < 4; ++ns)
            #pragma unroll
            for (int ch = 0; ch < 2; ++ch)
                bf[ns][ch] = *(const h8*)&ws[m][SWZ(ns * 16 + l15, ch * 4 + qd)];
        #pragma unroll
        for (int ns = 0; ns < 4; ++ns)
            acc[m][ns] = (f4){0.f, 0.f, 0.f, 0.f};
        #pragma unroll
        for (int ch = 0; ch < 2; ++ch)
            #pragma unroll
            for (int ns = 0; ns < 4; ++ns)
                acc[m][ns] = __builtin_amdgcn_mfma_f32_16x16x32_f16(
                    af[ch], bf[ns][ch], acc[m][ns], 0, 0, 0);
    }

    __syncthreads();                                        // sync 2 (ws reads done)

    // Write all three layout tiles into ws[m]
    #pragma unroll
    for (int m = 0; m < 2; ++m) {
        #pragma unroll
        for (int ns = 0; ns < 4; ++ns) {
            const int d = ns * 16 + l15;
            const float bias = bsh[m][d];
            #pragma unroll
            for (int r = 0; r < 4; ++r) {
                const int t = w * 16 + qd * 4 + r;
                float v = acc[m][ns][r] + bias;
                if (m == 0) v *= QSCALE;
                ws[m][SWZ(t, d >> 3) + (d & 7)] = (_Float16)v;
            }
        }
    }
    #pragma unroll
    for (int ns = 0; ns < 4; ++ns) {
        const int d = ns * 16 + l15;
        const float bias = bsh[2][d];
        const int tl = w * 16 + qd * 4;
        f4 pvf;
        #pragma unroll
        for (int r = 0; r < 4; ++r)
            pvf[r] = acc[2][ns][r] + bias;
        *(h4*)&ws[2][SWZ(d, tl >> 3) + (tl & 7)] = cvt4(pvf);
    }

    __syncthreads();                                        // sync 3

    // Copy-outs: all 6 stores issue back-to-back (no more syncs)
    #pragma unroll
    for (int pass = 0; pass < 2; ++pass) {
        const int t  = pass * 32 + (tid >> 3);
        const int c0 = (tid & 7) * 8;
        *(h8*)&qh[(size_t)(row0 + t) * 64 + c0] =
            *(const h8*)&ws[0][SWZ(t, tid & 7)];
    }
    // khT: f = kb*2048 + cs*512 + l*8 + e <->
    //      K_true[t0 + kb*32 + sigma(l&31)][cs*16 + (l>>5)*8 + e]
    #pragma unroll
    for (int pass = 0; pass < 2; ++pass) {
        const int f   = pass * 2048 + tid * 8;
        const int kb  = f >> 11;
        const int cs  = (f >> 9) & 3;
        const int l   = (f >> 3) & 63;
        const int p   = l & 31;
        const int w16 = p & 15;
        const int sw  = ((w16 & 12) == 4) ? (w16 + 4)
                      : (((w16 & 12) == 8) ? (w16 - 4) : w16);
        const int tact = kb * 32 + (p & 16) + sw;
        const int g8   = cs * 2 + (l >> 5);
        *(h8*)&khT[(size_t)head * HSTRIDE + (t0 >> 6) * 4096 + f] =
            *(const h8*)&ws[1][SWZ(tact, g8)];
    }
    // vtT: f = (b*2+cc)*512 + l*8 + e <-> V[t0 + b*16 + (l>>5)*8 + e][cc*32 + (l&31)]
    #pragma unroll
    for (int pass = 0; pass < 2; ++pass) {
        const int f  = pass * 2048 + tid * 8;
        const int q2 = f >> 9;
        const int b  = q2 >> 1, cc = q2 & 1;
        const int l  = (f >> 3) & 63;
        const int c  = cc * 32 + (l & 31);
        const int tg = b * 2 + (l >> 5);
        *(h8*)&vtT[(size_t)head * HSTRIDE + (t0 >> 6) * 4096 + f] =
            *(const h8*)&ws[2][SWZ(c, tg)];
    }
}

// ---------------------------------------------------------------------------
// Flash attention, barrier-free main loop, kt-split x4.
// 1024 blocks x 256 thr = 4 waves/block, 4 blocks/CU (natural occupancy:
// ~116 VGPR <= 128 threshold -> 4 waves/SIMD; LDS 33.8KB x4 = 135KB/CU).
// Block = (head, 64-q chunk); wave w covers kt-quarter w (8 tiles of 64 kt).
// K/V fragments loaded straight from L2 (khT/vtT fragment-linear, 16B/lane).
// Merge (fixed-SOFF softmax => partials add linearly):
//   R1: waves 2,3 export (oacc+lsum) -> waves 0,1 add.
//   R2: wave0 exports qs=1 -> wave1; wave1 exports qs=0 -> wave0.
//   Finalize: wave0 stores qs=0 rows, wave1 stores qs=1 rows.
// 3 barriers total. All oacc/ls subscripts compile-time (rule #20).
// ---------------------------------------------------------------------------
__global__ __launch_bounds__(256, 2) void attn_kernel(
    const _Float16* __restrict__ qh, const _Float16* __restrict__ khT,
    const _Float16* __restrict__ vtT, float* __restrict__ out)
{
    __shared__ float xbuf[2][4224];      // 4096 oacc + 128 lsum per exporter

    const int tid  = threadIdx.x;
    const int w    = tid >> 6;          // 0..3 = kt-quarter
    const int lane = tid & 63;
    const int l31  = lane & 31;
    const int lh   = lane >> 5;

    // XCD-aware mapping: all 32 blocks of a head share bid&7 (same XCD)
    const int bid  = blockIdx.x;
    const int xcd  = bid & 7;
    const int idx  = bid >> 3;               // 0..127
    const int head = xcd * 4 + (idx >> 5);
    const int qchunk = idx & 31;
    const int q0   = qchunk * 64;

    // Q B-frags: col = l&31 = q (within 32-block qs), k = 8*lh + e (+16*cs)
    h8 qf[2][4];
    #pragma unroll
    for (int qs = 0; qs < 2; ++qs) {
        const _Float16* qp = qh + (size_t)(head * T_DIM + q0 + qs * 32 + l31) * 64 + lh * 8;
        #pragma unroll
        for (int cs = 0; cs < 4; ++cs)
            qf[qs][cs] = *(const h8*)(qp + cs * 16);
    }

    const int ko = lane * 8;
    const _Float16* kbase = khT + (size_t)head * HSTRIDE + (size_t)w * 8 * 4096;
    const _Float16* vbase = vtT + (size_t)head * HSTRIDE + (size_t)w * 8 * 4096;

    f4 rs4[2] = {(f4){0.f,0.f,0.f,0.f}, (f4){0.f,0.f,0.f,0.f}};
    fv16 oacc[2][2];
    #pragma unroll
    for (int qs = 0; qs < 2; ++qs)
        #pragma unroll
        for (int cc = 0; cc < 2; ++cc)
            oacc[qs][cc] = splat16(0.f);

    // prologue: fragment loads for tile 0 of this quarter
    h8 kf[2][4];
    h8 vf[4][2];
    #pragma unroll
    for (int kb = 0; kb < 2; ++kb)
        #pragma unroll
        for (int cs = 0; cs < 4; ++cs)
            kf[kb][cs] = *(const h8*)(kbase + kb * 2048 + cs * 512 + ko);
    #pragma unroll
    for (int b = 0; b < 4; ++b)
        #pragma unroll
        for (int cc = 0; cc < 2; ++cc)
            vf[b][cc] = *(const h8*)(vbase + (b * 2 + cc) * 512 + ko);

    for (int it = 0; it < 8; ++it) {
        const _Float16* kn = kbase + (size_t)(it + 1) * 4096;
        const _Float16* vn = vbase + (size_t)(it + 1) * 4096;
        const bool more = (it < 7);

        #pragma unroll
        for (int kb = 0; kb < 2; ++kb) {
            // QK for this kb (st kept to 32 regs: 2 qs x fv16)
            fv16 st2[2];
            st2[0] = splat16(-SOFF);
            st2[1] = splat16(-SOFF);
            #pragma unroll
            for (int cs = 0; cs < 4; ++cs)
                #pragma unroll
                for (int qs = 0; qs < 2; ++qs)
                    st2[qs] = __builtin_amdgcn_mfma_f32_32x32x16_f16(
                        kf[kb][cs], qf[qs][cs], st2[qs], 0, 0, 0);

            // kf[kb] dead after QK issue -> reload next tile's kb block now;
            // the L2 load drains under the exp/PV below.
            if (more) {
                #pragma unroll
                for (int cs = 0; cs < 4; ++cs)
                    kf[kb][cs] = *(const h8*)(kn + kb * 2048 + cs * 512 + ko);
            }

            // softmax + PV for this kb
            #pragma unroll
            for (int qs = 0; qs < 2; ++qs) {
                f4 pg[4];
                #pragma unroll
                for (int g = 0; g < 4; ++g) {
                    pg[g][0] = EXP2(st2[qs][4 * g + 0]);
                    pg[g][1] = EXP2(st2[qs][4 * g + 1]);
                    pg[g][2] = EXP2(st2[qs][4 * g + 2]);
                    pg[g][3] = EXP2(st2[qs][4 * g + 3]);
                    rs4[qs] += pg[g];
                }
                H8U pa[2];
                #pragma unroll
                for (int g = 0; g < 4; ++g) {
                    pa[g >> 1].p[(g & 1) * 2 + 0] = __builtin_amdgcn_cvt_pkrtz(pg[g][0], pg[g][1]);
                    pa[g >> 1].p[(g & 1) * 2 + 1] = __builtin_amdgcn_cvt_pkrtz(pg[g][2], pg[g][3]);
                }
                #pragma unroll
                for (int bl = 0; bl < 2; ++bl)
                    #pragma unroll
                    for (int cc = 0; cc < 2; ++cc)
                        oacc[qs][cc] = __builtin_amdgcn_mfma_f32_32x32x16_f16(
                            pa[bl].v, vf[kb * 2 + bl][cc], oacc[qs][cc], 0, 0, 0);
            }

            // vf blocks for this kb dead -> reload next tile's; drains under
            // the next kb's / next iter's QK+exp.
            if (more) {
                #pragma unroll
                for (int bl = 0; bl < 2; ++bl)
                    #pragma unroll
                    for (int cc = 0; cc < 2; ++cc)
                        vf[kb * 2 + bl][cc] =
                            *(const h8*)(vn + ((kb * 2 + bl) * 2 + cc) * 512 + ko);
            }
        }
    }

    // pre-reduce rs to one scalar per lane per qs (value for q-col l31)
    float ls0, ls1;
    {
        float a = (rs4[0][0] + rs4[0][1]) + (rs4[0][2] + rs4[0][3]);
        a += __shfl_xor(a, 32, 64);
        ls0 = a;
        float b = (rs4[1][0] + rs4[1][1]) + (rs4[1][2] + rs4[1][3]);
        b += __shfl_xor(b, 32, 64);
        ls1 = b;
    }

    // ---- Round 1: waves 2,3 export everything; waves 0,1 add ----
    if (w >= 2) {
        float* xb = xbuf[w - 2];
        #pragma unroll
        for (int qs = 0; qs < 2; ++qs)
            #pragma unroll
            for (int cc = 0; cc < 2; ++cc)
                #pragma unroll
                for (int r = 0; r < 16; ++r)
                    xb[(qs * 2 + cc) * 1024 + r * 64 + lane] = oacc[qs][cc][r];
        xb[4096 + lane] = ls0;
        xb[4160 + lane] = ls1;
    }
    __syncthreads();                                       // barrier 1
    if (w < 2) {
        const float* xb = xbuf[w];
        #pragma unroll
        for (int qs = 0; qs < 2; ++qs)
            #pragma unroll
            for (int cc = 0; cc < 2; ++cc)
                #pragma unroll
                for (int r = 0; r < 16; ++r)
                    oacc[qs][cc][r] += xb[(qs * 2 + cc) * 1024 + r * 64 + lane];
        ls0 += xb[4096 + lane];
        ls1 += xb[4160 + lane];
    }
    __syncthreads();                                       // barrier 2

    // ---- Round 2: wave0 exports qs=1 (to wave1); wave1 exports qs=0 ----
    if (w == 0) {
        float* xb = xbuf[1];
        #pragma unroll
        for (int cc = 0; cc < 2; ++cc)
            #pragma unroll
            for (int r = 0; r < 16; ++r)
                xb[(2 + cc) * 1024 + r * 64 + lane] = oacc[1][cc][r];
        xb[4160 + lane] = ls1;
    } else if (w == 1) {
        float* xb = xbuf[0];
        #pragma unroll
        for (int cc = 0; cc < 2; ++cc)
            #pragma unroll
            for (int r = 0; r < 16; ++r)
                xb[cc * 1024 + r * 64 + lane] = oacc[0][cc][r];
        xb[4096 + lane] = ls0;
    }
    __syncthreads();                                       // barrier 3

    // ---- Finalize: wave0 -> qs=0 rows, wave1 -> qs=1 rows ----
    if (w == 0) {
        const float* xb = xbuf[0];
        fv16 of[2];
        #pragma unroll
        for (int cc = 0; cc < 2; ++cc)
            #pragma unroll
            for (int r = 0; r < 16; ++r)
                of[cc][r] = oacc[0][cc][r] + xb[cc * 1024 + r * 64 + lane];
        const float lt = ls0 + xb[4096 + lane];
        const float linv = 1.f / lt;
        #pragma unroll
        for (int r = 0; r < 16; ++r) {
            const int qrow = (r & 3) + 8 * (r >> 2) + 4 * lh;
            const float fac = __shfl(linv, qrow, 64);
            #pragma unroll
            for (int cc = 0; cc < 2; ++cc)
                out[(size_t)(head * T_DIM + q0 + qrow) * 64 + cc * 32 + l31] =
                    of[cc][r] * fac;
        }
    } else if (w == 1) {
        const float* xb = xbuf[1];
        fv16 of[2];
        #pragma unroll
        for (int cc = 0; cc < 2; ++cc)
            #pragma unroll
            for (int r = 0; r < 16; ++r)
                of[cc][r] = oacc[1][cc][r] + xb[(2 + cc) * 1024 + r * 64 + lane];
        const float lt = ls1 + xb[4160 + lane];
        const float linv = 1.f / lt;
        #pragma unroll
        for (int r = 0; r < 16; ++r) {
            const int qrow = (r & 3) + 8 * (r >> 2) + 4 * lh;
            const float fac = __shfl(linv, qrow, 64);
            #pragma unroll
            for (int cc = 0; cc < 2; ++cc)
                out[(size_t)(head * T_DIM + q0 + 32 + qrow) * 64 + cc * 32 + l31] =
                    of[cc][r] * fac;
        }
    }
}

extern "C" void kernel_launch(void* const* d_in, const int* in_sizes, int n_in,
                              void* d_out, int out_size, void* d_ws, size_t ws_size,
                              hipStream_t stream)
{
    (void)in_sizes; (void)n_in; (void)out_size; (void)ws_size;
    const float* x  = (const float*)d_in[0];
    const float* Wq = (const float*)d_in[1];
    const float* bq = (const float*)d_in[2];
    const float* Wk = (const float*)d_in[3];
    const float* bk = (const float*)d_in[4];
    const float* Wv = (const float*)d_in[5];
    const float* bv = (const float*)d_in[6];
    float* out = (float*)d_out;

    _Float16* qh  = (_Float16*)d_ws;
    _Float16* khT = qh + (size_t)NHEAD * HSTRIDE;
    _Float16* vtT = khT + (size_t)NHEAD * HSTRIDE;

    hipLaunchKernelGGL(qkv_proj_kernel, dim3(1024), dim3(256), 0, stream,
                       x, Wq, bq, Wk, bk, Wv, bv, qh, khT, vtT);
    hipLaunchKernelGGL(attn_kernel, dim3(1024), dim3(256), 0, stream,
                       qh, khT, vtT, out);
}